// Round 1
// baseline (157.773 us; speedup 1.0000x reference)
//
#include <hip/hip_runtime.h>
#include <hip/hip_bf16.h>
#include <stdint.h>

#define NROWS 8192
#define NDIM  512
#define MARGIN 0.3f
#define NT    2080     // 64*65/2 upper-triangular 128x128 blocks
#define GRID  768      // persistent blocks, 3/CU exactly
#define NPART (GRID * 4 + 128)  // per-wave loss partials + 128 class corrections

typedef __attribute__((ext_vector_type(16))) float floatx16;
typedef __attribute__((ext_vector_type(8)))  int   intx8;

// pack 4 floats -> 4 OCP e4m3 bytes (HW cvt, RNE, saturating)
__device__ inline unsigned cvt4_fp8(float4 f) {
  int v = 0;
  v = __builtin_amdgcn_cvt_pk_fp8_f32(f.x, f.y, v, false);
  v = __builtin_amdgcn_cvt_pk_fp8_f32(f.z, f.w, v, true);
  return (unsigned)v;
}

// fp32 -> fp8 e4m3, fully coalesced: lane i reads float4 i, writes u32 i
__global__ void convert_kernel(const float4* __restrict__ in, unsigned* __restrict__ out) {
  int i = blockIdx.x * blockDim.x + threadIdx.x;
  out[i] = cvt4_fp8(in[i]);
}

__device__ inline void gload_lds16(const void* g, void* l) {
  __builtin_amdgcn_global_load_lds(
      (const __attribute__((address_space(1))) unsigned int*)g,
      (__attribute__((address_space(3))) unsigned int*)l, 16, 0, 0);
}

// super-tile decode (8 diagonal supers of 36, then 28 off-diag of 64)
__device__ inline void decode_tile(int t, int& bi, int& bj) {
  if (t < 288) {
    int si = t / 36;
    int q  = t - si * 36;
    int ii = 0;
    while (q >= 8 - ii) { q -= 8 - ii; ii++; }
    bi = si * 8 + ii;
    bj = si * 8 + ii + q;
  } else {
    int q = t - 288;
    int s = q >> 6, r = q & 63;
    int si = 0;
    while (s >= 7 - si) { s -= 7 - si; si++; }
    int sj = si + 1 + s;
    bi = si * 8 + (r >> 3);
    bj = sj * 8 + (r & 7);
  }
}

// R16: persistent rolling-pipeline loss kernel, LABEL-FREE epilogue.
//   total = SUM_{all ordered (i,j)} negval(s_ij)   (this kernel)
//         + SUM_{same-label ordered (i,j)} [posval(s) - negval(s)]  (corr_kernel)
// Off-diag 128x128 tiles: full tile sum x2 (both orders); diag tiles: full
// 128x128 sum x1 (s_ij == s_ji bitwise: same fp8 dot, same MFMA chunk order).
// 768 persistent blocks each run 2-3 tiles with the 3-stage BK=64 pipeline
// rolling ACROSS tile boundaries: global stage index g, buf = g%3, per-wave
// s_waitcnt vmcnt(4) (own stage landed, next stays in flight), raw s_barrier,
// stage-after-barrier. Pipeline fills: 2080 -> 768. No stores inside the loop
// (per-wave weighted sum accumulated in regs, one store at kernel end).
__launch_bounds__(256, 3)
__global__ void loss_kernel(const unsigned char* __restrict__ Xb,
                            float* __restrict__ partials) {
  __shared__ __align__(16) unsigned char As[3][8192];   // 128 rows x 64 B
  __shared__ __align__(16) unsigned char Bs[3][8192];

  const int tid  = threadIdx.x;
  const int lane = tid & 63;
  const int w    = tid >> 6;
  const int wm   = w >> 1, wn = w & 1;   // 2x2 waves, 64x64 each
  const int g    = lane >> 5;            // MFMA k-group (0/1)
  const int m32  = lane & 31;
  const int srow = lane >> 2;
  const int sup  = lane & 3;

  const int ntile = (blockIdx.x + 2 * GRID < NT) ? 3 : 2;  // all blocks have >= 2
  const int GT = ntile * 8;

  // staging addresses for the tile currently being staged. Chunk lane d:
  // row = ch*16 + (d>>2), u_phys = d&3; u_log = u_phys ^ ((row>>2)&3)
  // (conflict-free b128 reads, R14-verified).
  unsigned gA[2], gB[2];
#define SETADDR(BI, BJ)                                                   \
  do {                                                                    \
    _Pragma("unroll")                                                     \
    for (int c = 0; c < 2; c++) {                                         \
      int ch  = w * 2 + c;                                                \
      int row = ch * 16 + srow;                                           \
      int ul  = sup ^ ((row >> 2) & 3);                                   \
      gA[c] = (unsigned)(((BI) * 128 + row) * NDIM + ul * 16);            \
      gB[c] = (unsigned)(((BJ) * 128 + row) * NDIM + ul * 16);            \
    }                                                                     \
  } while (0)

// stage K-step (H&7) of the current stage-tile into buf H%3
#define STAGE(H)                                                          \
  do {                                                                    \
    _Pragma("unroll")                                                     \
    for (int c = 0; c < 2; c++) {                                         \
      int ch = w * 2 + c;                                                 \
      gload_lds16(Xb + gA[c] + ((H) & 7) * 64, &As[(H) % 3][ch * 1024]);  \
      gload_lds16(Xb + gB[c] + ((H) & 7) * 64, &Bs[(H) % 3][ch * 1024]);  \
    }                                                                     \
  } while (0)

  {
    int bi0, bj0;
    decode_tile(blockIdx.x, bi0, bj0);
    SETADDR(bi0, bj0);
  }
  STAGE(0);
  STAGE(1);

  float wsum = 0.f;

  for (int tt = 0; tt < ntile; tt++) {
    floatx16 acc[2][2];
#pragma unroll
    for (int a = 0; a < 2; a++)
#pragma unroll
      for (int b = 0; b < 2; b++) acc[a][b] = (floatx16)(0.f);

#pragma unroll
    for (int kt = 0; kt < 8; kt++) {
      const int gg = tt * 8 + kt;
      // own stage gg landed; the next stage's 4 loads stay in flight
      if (gg < GT - 1) asm volatile("s_waitcnt vmcnt(4)" ::: "memory");
      else             asm volatile("s_waitcnt vmcnt(0)" ::: "memory");
      asm volatile("s_barrier" ::: "memory");        // raw: no lgkm drain
      const int h = gg + 2;
      if (h < GT) {                                  // rolling distance-2 prefetch
        if ((h & 7) == 0) {                          // crossed into next tile
          int nbi, nbj;
          decode_tile(blockIdx.x + (h >> 3) * GRID, nbi, nbj);
          SETADDR(nbi, nbj);
        }
        STAGE(h);
      }

      const int buf = gg % 3;
      // fragments: lane holds k = g*32 + [0,32) of its row as 2 x b128
      intx8 af[2], bf[2];
#pragma unroll
      for (int mt = 0; mt < 2; mt++) {
        const int row = wm * 64 + mt * 32 + m32;
        const int x = (row >> 2) & 3;
        int4 lo = *(const int4*)(&As[buf][row * 64 + ((2 * g)     ^ x) * 16]);
        int4 hi = *(const int4*)(&As[buf][row * 64 + ((2 * g + 1) ^ x) * 16]);
        intx8 f; f[0]=lo.x; f[1]=lo.y; f[2]=lo.z; f[3]=lo.w;
                 f[4]=hi.x; f[5]=hi.y; f[6]=hi.z; f[7]=hi.w;
        af[mt] = f;
      }
#pragma unroll
      for (int nt = 0; nt < 2; nt++) {
        const int row = wn * 64 + nt * 32 + m32;
        const int x = (row >> 2) & 3;
        int4 lo = *(const int4*)(&Bs[buf][row * 64 + ((2 * g)     ^ x) * 16]);
        int4 hi = *(const int4*)(&Bs[buf][row * 64 + ((2 * g + 1) ^ x) * 16]);
        intx8 f; f[0]=lo.x; f[1]=lo.y; f[2]=lo.z; f[3]=lo.w;
                 f[4]=hi.x; f[5]=hi.y; f[6]=hi.z; f[7]=hi.w;
        bf[nt] = f;
      }

      __builtin_amdgcn_s_setprio(1);
#pragma unroll
      for (int mt = 0; mt < 2; mt++)
#pragma unroll
        for (int nt = 0; nt < 2; nt++)
          acc[mt][nt] = __builtin_amdgcn_mfma_scale_f32_32x32x64_f8f6f4(
              af[mt], bf[nt], acc[mt][nt],
              0 /*A fmt: fp8 e4m3*/, 0 /*B fmt: fp8 e4m3*/,
              0, 127 /*scaleA = 2^0*/, 0, 127 /*scaleB = 2^0*/);
      __builtin_amdgcn_s_setprio(0);
    }

    // label-free epilogue: 3 VALU/elem (cmp, cndmask, add)
    float lsum = 0.f;
#pragma unroll
    for (int mt = 0; mt < 2; mt++)
#pragma unroll
      for (int nt = 0; nt < 2; nt++)
#pragma unroll
        for (int e = 0; e < 16; e++) {
          const float s = acc[mt][nt][e];
          lsum += (s > MARGIN) ? s : 0.f;
        }
    int bi, bj;
    decode_tile(blockIdx.x + tt * GRID, bi, bj);
    wsum += (bi == bj) ? lsum : 2.f * lsum;
  }

  // per-wave partial, one store per wave, no block sync needed
#pragma unroll
  for (int off = 32; off > 0; off >>= 1) wsum += __shfl_down(wsum, off, 64);
  if (lane == 0) partials[blockIdx.x * 4 + w] = wsum;
#undef STAGE
#undef SETADDR
}

// Per-class correction: for all ORDERED same-label pairs (incl. i==j),
// add posval(s) - negval(s). Recomputes s from the SAME fp8 bytes with the
// SAME 8 x (32x32x64) MFMA chunking -> bitwise-identical s -> exact cancel.
#define MMAX 112   // max class size supported (mean 64, sd ~8; 6-sigma)
#define RSTR 528   // LDS row stride (512+16 B): rotates bank groups, ~4-way max
__global__ void corr_kernel(const unsigned char* __restrict__ Xb,
                            const int* __restrict__ tg,
                            float* __restrict__ partials) {
  __shared__ __align__(16) unsigned char Arows[MMAX * RSTR];  // ~59 KB
  __shared__ int idx[MMAX];
  __shared__ int wtot[4];
  __shared__ float red[4];

  const int c    = blockIdx.x;      // class id 0..127
  const int tid  = threadIdx.x;
  const int lane = tid & 63;
  const int w    = tid >> 6;

  // count matches in my 32-label chunk (stable chunk-major order)
  int cnt = 0;
#pragma unroll 4
  for (int j = 0; j < 32; j++) cnt += (tg[tid * 32 + j] == c) ? 1 : 0;
  // wave inclusive scan
  int inc = cnt;
#pragma unroll
  for (int off = 1; off < 64; off <<= 1) {
    int u = __shfl_up(inc, off, 64);
    if (lane >= off) inc += u;
  }
  if (lane == 63) wtot[w] = inc;
  __syncthreads();
  int woff = 0;
  for (int ww = 0; ww < w; ww++) woff += wtot[ww];
  const int excl = woff + inc - cnt;
  int m = wtot[0] + wtot[1] + wtot[2] + wtot[3];
  if (m > MMAX) m = MMAX;
  // write gathered row indices
  int k = excl;
  for (int j = 0; j < 32; j++) {
    const int ii = tid * 32 + j;
    if (tg[ii] == c) { if (k < MMAX) idx[k] = ii; k++; }
  }
  __syncthreads();

  const int nm = (m + 31) >> 5;          // 32-row tiles (<= 4)
  // gather class rows into LDS (zero-pad to nm*32 rows)
  const int pieces = nm * 32 * 32;       // rows x 32 16B-pieces
  for (int p = tid; p < pieces; p += 256) {
    const int r = p >> 5, u = p & 31;
    int4 v = make_int4(0, 0, 0, 0);
    if (r < m) v = *(const int4*)(Xb + (size_t)idx[r] * NDIM + u * 16);
    *(int4*)(&Arows[r * RSTR + u * 16]) = v;
  }
  __syncthreads();

  const int g   = lane >> 5;
  const int m32 = lane & 31;
  float corr = 0.f;
  for (int tq = w; tq < nm * nm; tq += 4) {
    const int ti = tq / nm, tj = tq % nm;
    floatx16 acc = (floatx16)(0.f);
#pragma unroll
    for (int kt = 0; kt < 8; kt++) {
      // k = kt*64 + g*32 + [0,32): pieces kt*4 + 2g, 2g+1 of the row
      const unsigned char* pa = &Arows[(ti * 32 + m32) * RSTR + (kt * 4 + 2 * g) * 16];
      const unsigned char* pb = &Arows[(tj * 32 + m32) * RSTR + (kt * 4 + 2 * g) * 16];
      int4 alo = *(const int4*)pa,  ahi = *(const int4*)(pa + 16);
      int4 blo = *(const int4*)pb,  bhi = *(const int4*)(pb + 16);
      intx8 a; a[0]=alo.x; a[1]=alo.y; a[2]=alo.z; a[3]=alo.w;
               a[4]=ahi.x; a[5]=ahi.y; a[6]=ahi.z; a[7]=ahi.w;
      intx8 b; b[0]=blo.x; b[1]=blo.y; b[2]=blo.z; b[3]=blo.w;
               b[4]=bhi.x; b[5]=bhi.y; b[6]=bhi.z; b[7]=bhi.w;
      acc = __builtin_amdgcn_mfma_scale_f32_32x32x64_f8f6f4(
          a, b, acc, 0, 0, 0, 127, 0, 127);
    }
    // 32x32 C layout: col = lane&31, row = (reg&3) + 8*(reg>>2) + 4*(lane>>5)
#pragma unroll
    for (int q = 0; q < 4; q++)
#pragma unroll
      for (int j = 0; j < 4; j++) {
        const int row = ti * 32 + j + 8 * q + 4 * g;
        const int col = tj * 32 + m32;
        if (row < m && col < m) {
          const float s  = acc[q * 4 + j];
          const float pv = (s < 1.f) ? (1.f - s) : 0.f;
          const float nv = (s > MARGIN) ? s : 0.f;
          corr += pv - nv;
        }
      }
  }
#pragma unroll
  for (int off = 32; off > 0; off >>= 1) corr += __shfl_down(corr, off, 64);
  if (lane == 0) red[w] = corr;
  __syncthreads();
  if (tid == 0) partials[GRID * 4 + c] = red[0] + red[1] + red[2] + red[3];
}

// NPART partials -> scalar; one 256-thread block
__global__ void reduce_kernel(const float* __restrict__ partials, float* __restrict__ out) {
  __shared__ float red[4];
  float s = 0.f;
  for (int i = threadIdx.x; i < NPART; i += 256) s += partials[i];
#pragma unroll
  for (int off = 32; off > 0; off >>= 1) s += __shfl_down(s, off, 64);
  if ((threadIdx.x & 63) == 0) red[threadIdx.x >> 6] = s;
  __syncthreads();
  if (threadIdx.x == 0)
    out[0] = (red[0] + red[1] + red[2] + red[3]) * (1.0f / NROWS);
}

extern "C" void kernel_launch(void* const* d_in, const int* in_sizes, int n_in,
                              void* d_out, int out_size, void* d_ws, size_t ws_size,
                              hipStream_t stream) {
  const float* x = (const float*)d_in[0];
  const int* tg  = (const int*)d_in[1];
  float* out     = (float*)d_out;
  unsigned char* xb = (unsigned char*)d_ws;                    // fp8 X, 4 MiB
  float* partials   = (float*)((char*)d_ws + (4u << 20));      // NPART floats

  convert_kernel<<<(NROWS * NDIM / 4) / 256, 256, 0, stream>>>(
      (const float4*)x, (unsigned*)xb);
  loss_kernel<<<GRID, 256, 0, stream>>>(xb, partials);
  corr_kernel<<<128, 256, 0, stream>>>(xb, tg, partials);
  reduce_kernel<<<1, 256, 0, stream>>>(partials, out);
}

// Round 2
// 104.921 us; speedup vs baseline: 1.5037x; 1.5037x over previous
//
#include <hip/hip_runtime.h>
#include <hip/hip_bf16.h>
#include <stdint.h>

#define NROWS 8192
#define NDIM  512
#define MARGIN 0.3f
#define NT    2080             // 64*65/2 upper-triangular 128x128 blocks
#define NPART (NT + 256)       // per-block loss partials + 256 class-correction partials

typedef __attribute__((ext_vector_type(16))) float floatx16;
typedef __attribute__((ext_vector_type(8)))  int   intx8;

// pack 4 floats -> 4 OCP e4m3 bytes (HW cvt, RNE, saturating)
__device__ inline unsigned cvt4_fp8(float4 f) {
  int v = 0;
  v = __builtin_amdgcn_cvt_pk_fp8_f32(f.x, f.y, v, false);
  v = __builtin_amdgcn_cvt_pk_fp8_f32(f.z, f.w, v, true);
  return (unsigned)v;
}

// fp32 -> fp8 e4m3, fully coalesced: lane i reads float4 i, writes u32 i
__global__ void convert_kernel(const float4* __restrict__ in, unsigned* __restrict__ out) {
  int i = blockIdx.x * blockDim.x + threadIdx.x;
  out[i] = cvt4_fp8(in[i]);
}

__device__ inline void gload_lds16(const void* g, void* l) {
  __builtin_amdgcn_global_load_lds(
      (const __attribute__((address_space(1))) unsigned int*)g,
      (__attribute__((address_space(3))) unsigned int*)l, 16, 0, 0);
}

// XCD-grouped block->tile decode. Dispatch round-robins blockIdx across the
// 8 XCDs (b%8 = XCD). We arrange that all tiles of one 1024x1024 super-tile
// land on ONE XCD, so the per-XCD L2 working set is ~1-3 MiB (< 4 MiB L2)
// instead of all of X (R1 counters: FETCH_SIZE=122MB = 30x re-fetch of the
// 4MB input from HBM because every XCD touched every row band).
//   diag supers   (8 x 36 tiles): b = si + 8*k          -> XCD si
//   off-diag 0-23 (3 groups of 8): b = 288 + g*512 + (u%8) + 8*r -> XCD u%8
//   off-diag 24-27 (4 supers, 2 XCDs each): b = 1824 + (u-24) + 4*(r&1) + 8*(r>>1)
// Bijective over [0,2080).
__device__ inline void decode_block(int b, int& bi, int& bj) {
  if (b < 288) {
    int si = b & 7;
    int q  = b >> 3;           // 0..35 within diag super
    int ii = 0;
    while (q >= 8 - ii) { q -= 8 - ii; ii++; }
    bi = si * 8 + ii;
    bj = si * 8 + ii + q;
  } else {
    int u, r;
    if (b < 1824) {
      int q = b - 288;
      u = ((q >> 9) << 3) + (q & 7);
      r = (q >> 3) & 63;
    } else {
      int d = b - 1824;
      u = 24 + (d & 3);
      r = ((d >> 3) << 1) | ((d >> 2) & 1);
    }
    int s = u;
    int si = 0;
    while (s >= 7 - si) { s -= 7 - si; si++; }
    int sj = si + 1 + s;
    bi = si * 8 + (r >> 3);
    bj = sj * 8 + (r & 7);
  }
}

// R17 = R15 pipeline (known-good ~44us) + XCD-grouped tiles + label-free
// epilogue. total = SUM_{all ordered (i,j)} negval(s_ij)      (this kernel)
//                 + SUM_{same-label ordered} [posval - negval] (corr_kernel)
// Off-diag tiles: full 128x128 sum x2 (both orders); diag tiles: full sum x1
// (s_ij == s_ji bitwise: same fp8 bytes, same MFMA k-order; R1-verified).
// 3-stage BK=64 LDS (48 KB -> 3 blocks/CU), prefetch distance TWO, per-wave
// s_waitcnt vmcnt(4) mid-loop (own stage landed, next stays in flight), raw
// s_barrier (no lgkm drain), stage-after-barrier (WAR barrier-ordered).
__launch_bounds__(256, 3)
__global__ void loss_kernel(const unsigned char* __restrict__ Xb,
                            float* __restrict__ partials) {
  __shared__ __align__(16) unsigned char As[3][8192];   // 128 rows x 64 B
  __shared__ __align__(16) unsigned char Bs[3][8192];
  __shared__ float red[4];

  int bi, bj;
  decode_block(blockIdx.x, bi, bj);

  const int tid  = threadIdx.x;
  const int lane = tid & 63;
  const int w    = tid >> 6;
  const int wm   = w >> 1, wn = w & 1;   // 2x2 waves, 64x64 each
  const int g    = lane >> 5;            // MFMA k-group (0/1)
  const int m32  = lane & 31;            // MFMA row/col within 32

  const int rowBase = bi * 128;
  const int colBase = bj * 128;

  // staging: tile = 128 rows x 64 B = 8 chunks of 1 KB (16 rows each);
  // wave w stages chunks {2w, 2w+1} of A and of B (4 DMA loads/wave/stage).
  // Chunk lane d: row = ch*16 + (d>>2), u_phys = d&3; fetches global k-unit
  // u_log = u_phys ^ ((row>>2)&3)  (conflict-free b128 reads, R14-verified).
  const int srow = lane >> 2;
  const int sup  = lane & 3;
  unsigned gA[2], gB[2];
#pragma unroll
  for (int c = 0; c < 2; c++) {
    int ch  = w * 2 + c;
    int row = ch * 16 + srow;
    int ul  = sup ^ ((row >> 2) & 3);
    gA[c] = (unsigned)((rowBase + row) * NDIM + ul * 16);
    gB[c] = (unsigned)((colBase + row) * NDIM + ul * 16);
  }

#define STAGE(KT, BUF)                                                    \
  do {                                                                    \
    _Pragma("unroll")                                                     \
    for (int c = 0; c < 2; c++) {                                         \
      int ch = w * 2 + c;                                                 \
      gload_lds16(Xb + gA[c] + (KT) * 64, &As[BUF][ch * 1024]);           \
      gload_lds16(Xb + gB[c] + (KT) * 64, &Bs[BUF][ch * 1024]);           \
    }                                                                     \
  } while (0)

  floatx16 acc[2][2];
#pragma unroll
  for (int a = 0; a < 2; a++)
#pragma unroll
    for (int b = 0; b < 2; b++) acc[a][b] = (floatx16)(0.f);

  STAGE(0, 0);
  STAGE(1, 1);

#pragma unroll
  for (int kt = 0; kt < 8; kt++) {
    const int buf = kt % 3;
    // tile kt landed (own 4 oldest loads retired); kt+1's 4 stay in flight.
    if (kt < 7) asm volatile("s_waitcnt vmcnt(4)" ::: "memory");
    else        asm volatile("s_waitcnt vmcnt(0)" ::: "memory");
    asm volatile("s_barrier" ::: "memory");        // raw: no lgkm drain
    if (kt < 6) STAGE(kt + 2, (kt + 2) % 3);       // distance-2 prefetch

    // fragments: lane holds k = g*32 + [0,32) of its row as 2 x b128
    // (u_log = 2g, 2g+1), un-swizzled via u_phys = u_log ^ ((row>>2)&3)
    intx8 af[2], bf[2];
#pragma unroll
    for (int mt = 0; mt < 2; mt++) {
      const int row = wm * 64 + mt * 32 + m32;
      const int x = (row >> 2) & 3;
      int4 lo = *(const int4*)(&As[buf][row * 64 + ((2 * g)     ^ x) * 16]);
      int4 hi = *(const int4*)(&As[buf][row * 64 + ((2 * g + 1) ^ x) * 16]);
      intx8 f; f[0]=lo.x; f[1]=lo.y; f[2]=lo.z; f[3]=lo.w;
               f[4]=hi.x; f[5]=hi.y; f[6]=hi.z; f[7]=hi.w;
      af[mt] = f;
    }
#pragma unroll
    for (int nt = 0; nt < 2; nt++) {
      const int row = wn * 64 + nt * 32 + m32;
      const int x = (row >> 2) & 3;
      int4 lo = *(const int4*)(&Bs[buf][row * 64 + ((2 * g)     ^ x) * 16]);
      int4 hi = *(const int4*)(&Bs[buf][row * 64 + ((2 * g + 1) ^ x) * 16]);
      intx8 f; f[0]=lo.x; f[1]=lo.y; f[2]=lo.z; f[3]=lo.w;
               f[4]=hi.x; f[5]=hi.y; f[6]=hi.z; f[7]=hi.w;
      bf[nt] = f;
    }
#pragma unroll
    for (int mt = 0; mt < 2; mt++)
#pragma unroll
      for (int nt = 0; nt < 2; nt++)
        acc[mt][nt] = __builtin_amdgcn_mfma_scale_f32_32x32x64_f8f6f4(
            af[mt], bf[nt], acc[mt][nt],
            0 /*A fmt: fp8 e4m3*/, 0 /*B fmt: fp8 e4m3*/,
            0, 127 /*scaleA = 2^0*/, 0, 127 /*scaleB = 2^0*/);
  }

  // label-free epilogue: 3 VALU/elem (cmp, cndmask, add)
  float lsum = 0.f;
#pragma unroll
  for (int mt = 0; mt < 2; mt++)
#pragma unroll
    for (int nt = 0; nt < 2; nt++)
#pragma unroll
      for (int e = 0; e < 16; e++) {
        const float s = acc[mt][nt][e];
        lsum += (s > MARGIN) ? s : 0.f;
      }
  lsum *= (bi == bj) ? 1.f : 2.f;

  // block reduce, ONE non-atomic partial store per block
#pragma unroll
  for (int off = 32; off > 0; off >>= 1) lsum += __shfl_down(lsum, off, 64);
  if (lane == 0) red[w] = lsum;
  __syncthreads();
  if (tid == 0) partials[blockIdx.x] = red[0] + red[1] + red[2] + red[3];
#undef STAGE
}

// Per-class correction: for all ORDERED same-label pairs (incl. i==j),
// add posval(s) - negval(s). Recomputes s from the SAME fp8 bytes with the
// SAME 8 x (32x32x64) MFMA chunking -> bitwise-identical s -> exact cancel
// of the main kernel's negval (R1-verified, absmax 0.0).
// 2 blocks per class (256 blocks) to halve the serial tail.
#define MMAX 112   // max class size supported (mean 64, sd ~8; 6-sigma)
#define RSTR 528   // LDS row stride (512+16 B): rotates bank groups, ~4-way max
__global__ void corr_kernel(const unsigned char* __restrict__ Xb,
                            const int* __restrict__ tg,
                            float* __restrict__ partials) {
  __shared__ __align__(16) unsigned char Arows[MMAX * RSTR];  // ~59 KB
  __shared__ int idx[MMAX];
  __shared__ int wtot[4];
  __shared__ float red[4];

  const int c    = blockIdx.x >> 1;  // class id 0..127
  const int hh   = blockIdx.x & 1;   // half-split of the tile-pair space
  const int tid  = threadIdx.x;
  const int lane = tid & 63;
  const int w    = tid >> 6;

  // count matches in my 32-label chunk (stable chunk-major order)
  int cnt = 0;
#pragma unroll 4
  for (int j = 0; j < 32; j++) cnt += (tg[tid * 32 + j] == c) ? 1 : 0;
  // wave inclusive scan
  int inc = cnt;
#pragma unroll
  for (int off = 1; off < 64; off <<= 1) {
    int u = __shfl_up(inc, off, 64);
    if (lane >= off) inc += u;
  }
  if (lane == 63) wtot[w] = inc;
  __syncthreads();
  int woff = 0;
  for (int ww = 0; ww < w; ww++) woff += wtot[ww];
  const int excl = woff + inc - cnt;
  int m = wtot[0] + wtot[1] + wtot[2] + wtot[3];
  if (m > MMAX) m = MMAX;
  // write gathered row indices
  int k = excl;
  for (int j = 0; j < 32; j++) {
    const int ii = tid * 32 + j;
    if (tg[ii] == c) { if (k < MMAX) idx[k] = ii; k++; }
  }
  __syncthreads();

  const int nm = (m + 31) >> 5;          // 32-row tiles (<= 4)
  // gather class rows into LDS (zero-pad to nm*32 rows)
  const int pieces = nm * 32 * 32;       // rows x 32 16B-pieces
  for (int p = tid; p < pieces; p += 256) {
    const int r = p >> 5, u = p & 31;
    int4 v = make_int4(0, 0, 0, 0);
    if (r < m) v = *(const int4*)(Xb + (size_t)idx[r] * NDIM + u * 16);
    *(int4*)(&Arows[r * RSTR + u * 16]) = v;
  }
  __syncthreads();

  const int g   = lane >> 5;
  const int m32 = lane & 31;
  float corr = 0.f;
  for (int tq = w + 4 * hh; tq < nm * nm; tq += 8) {
    const int ti = tq / nm, tj = tq % nm;
    floatx16 acc = (floatx16)(0.f);
#pragma unroll
    for (int kt = 0; kt < 8; kt++) {
      // k = kt*64 + g*32 + [0,32): pieces kt*4 + 2g, 2g+1 of the row
      const unsigned char* pa = &Arows[(ti * 32 + m32) * RSTR + (kt * 4 + 2 * g) * 16];
      const unsigned char* pb = &Arows[(tj * 32 + m32) * RSTR + (kt * 4 + 2 * g) * 16];
      int4 alo = *(const int4*)pa,  ahi = *(const int4*)(pa + 16);
      int4 blo = *(const int4*)pb,  bhi = *(const int4*)(pb + 16);
      intx8 a; a[0]=alo.x; a[1]=alo.y; a[2]=alo.z; a[3]=alo.w;
               a[4]=ahi.x; a[5]=ahi.y; a[6]=ahi.z; a[7]=ahi.w;
      intx8 b; b[0]=blo.x; b[1]=blo.y; b[2]=blo.z; b[3]=blo.w;
               b[4]=bhi.x; b[5]=bhi.y; b[6]=bhi.z; b[7]=bhi.w;
      acc = __builtin_amdgcn_mfma_scale_f32_32x32x64_f8f6f4(
          a, b, acc, 0, 0, 0, 127, 0, 127);
    }
    // 32x32 C layout: col = lane&31, row = (reg&3) + 8*(reg>>2) + 4*(lane>>5)
#pragma unroll
    for (int q = 0; q < 4; q++)
#pragma unroll
      for (int j = 0; j < 4; j++) {
        const int row = ti * 32 + j + 8 * q + 4 * g;
        const int col = tj * 32 + m32;
        if (row < m && col < m) {
          const float s  = acc[q * 4 + j];
          const float pv = (s < 1.f) ? (1.f - s) : 0.f;
          const float nv = (s > MARGIN) ? s : 0.f;
          corr += pv - nv;
        }
      }
  }
#pragma unroll
  for (int off = 32; off > 0; off >>= 1) corr += __shfl_down(corr, off, 64);
  if (lane == 0) red[w] = corr;
  __syncthreads();
  if (tid == 0) partials[NT + blockIdx.x] = red[0] + red[1] + red[2] + red[3];
}

// NPART partials -> scalar; one 256-thread block
__global__ void reduce_kernel(const float* __restrict__ partials, float* __restrict__ out) {
  __shared__ float red[4];
  float s = 0.f;
  for (int i = threadIdx.x; i < NPART; i += 256) s += partials[i];
#pragma unroll
  for (int off = 32; off > 0; off >>= 1) s += __shfl_down(s, off, 64);
  if ((threadIdx.x & 63) == 0) red[threadIdx.x >> 6] = s;
  __syncthreads();
  if (threadIdx.x == 0)
    out[0] = (red[0] + red[1] + red[2] + red[3]) * (1.0f / NROWS);
}

extern "C" void kernel_launch(void* const* d_in, const int* in_sizes, int n_in,
                              void* d_out, int out_size, void* d_ws, size_t ws_size,
                              hipStream_t stream) {
  const float* x = (const float*)d_in[0];
  const int* tg  = (const int*)d_in[1];
  float* out     = (float*)d_out;
  unsigned char* xb = (unsigned char*)d_ws;                    // fp8 X, 4 MiB
  float* partials   = (float*)((char*)d_ws + (4u << 20));      // NPART floats

  convert_kernel<<<(NROWS * NDIM / 4) / 256, 256, 0, stream>>>(
      (const float4*)x, (unsigned*)xb);
  loss_kernel<<<NT, 256, 0, stream>>>(xb, partials);
  corr_kernel<<<256, 256, 0, stream>>>(xb, tg, partials);
  reduce_kernel<<<1, 256, 0, stream>>>(partials, out);
}